// Round 1
// baseline (999.690 us; speedup 1.0000x reference)
//
#include <hip/hip_runtime.h>

#define NNODE 16384
#define DD 32
#define INPC 256
#define UC 128
#define RC 8
#define EC 8

// ---------- prep: P = (q_w @ k_w^T) / U ----------
__global__ void k_qkt(const float* __restrict__ qw, const float* __restrict__ kw,
                      float* __restrict__ P) {
    int id = blockIdx.x * 256 + threadIdx.x;      // 64 blocks * 256 = 16384 = 128*128
    int i = id >> 7, j = id & 127;
    const float4* qr = (const float4*)(qw + i * UC);   // wave-uniform row -> s_loads
    const float4* kr = (const float4*)(kw + j * UC);   // per-lane row (small, L2-hot)
    float acc = 0.f;
    #pragma unroll
    for (int lc = 0; lc < 32; ++lc) {
        float4 a = qr[lc], b = kr[lc];
        acc += a.x * b.x + a.y * b.y + a.z * b.z + a.w * b.w;
    }
    P[id] = acc * (1.0f / 128.0f);
}

// ---------- prep: M[r] = P @ rel_w[r]^T ; RV[r] = rel_w[r] @ v_w ----------
__global__ void k_mrv(const float* __restrict__ P, const float* __restrict__ relw,
                      const float* __restrict__ vw, float* __restrict__ Mmat,
                      float* __restrict__ RVmat) {
    int r = blockIdx.x, i0 = blockIdx.y * 16;
    const float* R = relw + r * UC * UC;
    int j = threadIdx.x & 127, h = threadIdx.x >> 7;

    float accM[8] = {0,0,0,0,0,0,0,0};
    for (int mc = 0; mc < 32; ++mc) {
        float4 rv = *(const float4*)&R[j * UC + mc * 4];     // rel row j
        #pragma unroll
        for (int ii = 0; ii < 8; ++ii) {
            float4 p = *(const float4*)&P[(i0 + h * 8 + ii) * UC + mc * 4]; // uniform
            accM[ii] += p.x * rv.x + p.y * rv.y + p.z * rv.z + p.w * rv.w;
        }
    }
    #pragma unroll
    for (int ii = 0; ii < 8; ++ii)
        Mmat[(r * UC + (i0 + h * 8 + ii)) * UC + j] = accM[ii];

    float accV[8] = {0,0,0,0,0,0,0,0};
    for (int m = 0; m < UC; ++m) {
        float v = vw[m * UC + j];                            // coalesced
        #pragma unroll
        for (int ii = 0; ii < 8; ++ii)
            accV[ii] += R[(i0 + h * 8 + ii) * UC + m] * v;   // uniform
    }
    #pragma unroll
    for (int ii = 0; ii < 8; ++ii)
        RVmat[(r * UC + (i0 + h * 8 + ii)) * UC + j] = accV[ii];
}

// ---------- compaction by entity ----------
__global__ void k_count(const int* __restrict__ pe, int* __restrict__ cnt) {
    int n = blockIdx.x * 256 + threadIdx.x;
    atomicAdd(&cnt[pe[n]], 1);
}
__global__ void k_scan(const int* __restrict__ cnt, int* __restrict__ base) {
    if (threadIdx.x == 0) {
        int run = 0;
        for (int e = 0; e < EC; ++e) { base[e] = run; run += cnt[e]; }
    }
}
__global__ void k_scatter(const int* __restrict__ pe, const int* __restrict__ base,
                          int* __restrict__ cnt2, int* __restrict__ list) {
    int n = blockIdx.x * 256 + threadIdx.x;
    int e = pe[n];
    int pos = base[e] + atomicAdd(&cnt2[e], 1);
    list[pos] = n;
}

// ---------- center[n] = node_state[n] @ point_enc_w[pe[n]]  (per-entity tiles) ----------
__global__ void k_center(const float* __restrict__ ns, const float* __restrict__ pew,
                         const int* __restrict__ list, const int* __restrict__ cnt,
                         const int* __restrict__ base, float* __restrict__ center) {
    int e = blockIdx.y;
    int start = blockIdx.x * 32;
    int c = cnt[e];
    if (start >= c) return;
    int m = min(32, c - start);

    __shared__ float ns_s[32 * 256];   // 32 KB
    __shared__ int ids_s[32];
    if ((int)threadIdx.x < m) ids_s[threadIdx.x] = list[base[e] + start + threadIdx.x];
    __syncthreads();
    for (int idx = threadIdx.x; idx < m * 256; idx += 256)
        ns_s[idx] = ns[ids_s[idx >> 8] * INPC + (idx & 255)];
    __syncthreads();

    int j = threadIdx.x & 127, h = threadIdx.x >> 7;   // 2 groups x 16 rows
    const float* W = pew + (size_t)e * INPC * UC;
    float acc[16];
    #pragma unroll
    for (int rr = 0; rr < 16; ++rr) acc[rr] = 0.f;

    for (int kc = 0; kc < 64; ++kc) {
        float w0 = W[(kc * 4 + 0) * UC + j];
        float w1 = W[(kc * 4 + 1) * UC + j];
        float w2 = W[(kc * 4 + 2) * UC + j];
        float w3 = W[(kc * 4 + 3) * UC + j];
        #pragma unroll
        for (int rr = 0; rr < 16; ++rr) {
            float4 nv = *(const float4*)&ns_s[(h * 16 + rr) * 256 + kc * 4]; // broadcast
            acc[rr] += nv.x * w0 + nv.y * w1 + nv.z * w2 + nv.w * w3;
        }
    }
    #pragma unroll
    for (int rr = 0; rr < 16; ++rr) {
        int row = h * 16 + rr;
        if (row < m) center[ids_s[row] * UC + j] = acc[rr];
    }
}

// ---------- fused: qr = center @ M[r] (LDS), scores, softmax -> attn ----------
__global__ void k_scores(const float* __restrict__ center, const float* __restrict__ Mmat,
                         const int* __restrict__ adj, const int* __restrict__ rel,
                         float* __restrict__ attn) {
    __shared__ float qr_s[16 * 8 * 128];   // 64 KB
    int n0 = blockIdx.x * 16;
    int j = threadIdx.x & 127, h = threadIdx.x >> 7;

    float acc[8][8];   // [r][nn]
    #pragma unroll
    for (int r = 0; r < 8; ++r)
        #pragma unroll
        for (int nn = 0; nn < 8; ++nn) acc[r][nn] = 0.f;

    for (int kc = 0; kc < 32; ++kc) {
        float4 cv[8];
        #pragma unroll
        for (int nn = 0; nn < 8; ++nn)
            cv[nn] = *(const float4*)&center[(n0 + h * 8 + nn) * UC + kc * 4]; // uniform
        #pragma unroll
        for (int kk = 0; kk < 4; ++kk) {
            #pragma unroll
            for (int r = 0; r < 8; ++r) {
                float w = Mmat[(r * UC + kc * 4 + kk) * UC + j];  // coalesced, L2
                #pragma unroll
                for (int nn = 0; nn < 8; ++nn)
                    acc[r][nn] += ((const float*)&cv[nn])[kk] * w;
            }
        }
    }
    #pragma unroll
    for (int r = 0; r < 8; ++r)
        #pragma unroll
        for (int nn = 0; nn < 8; ++nn)
            qr_s[((h * 8 + nn) * 8 + r) * 128 + j] = acc[r][nn];
    __syncthreads();

    // phase B: one wave per node-quad, dot + butterfly-reduce, softmax over 32 edges
    int wv = threadIdx.x >> 6;
    int l  = threadIdx.x & 63;
    for (int q = 0; q < 4; ++q) {
        int tn = wv * 4 + q;
        int n = n0 + tn;
        const int* arow = adj + n * DD;
        const int* rrow = rel + n * DD;
        float myscore = 0.f;
        for (int d = 0; d < 32; ++d) {
            int rd = rrow[d];               // wave-uniform
            int ai = arow[d];               // wave-uniform
            float x1 = 0.f, x2 = 0.f;
            if (ai > 0) {
                const float* xp = center + (size_t)(ai - 1) * UC;
                x1 = xp[l]; x2 = xp[l + 64];
            }
            float q1 = qr_s[(tn * 8 + rd) * 128 + l];
            float q2 = qr_s[(tn * 8 + rd) * 128 + l + 64];
            float p = x1 * q1 + x2 * q2;
            #pragma unroll
            for (int off = 32; off > 0; off >>= 1)
                p += __shfl_xor(p, off, 64);
            if (rd == 0) p = -1e9f;
            if (l == d) myscore = p;
        }
        float mx = myscore;
        #pragma unroll
        for (int off = 16; off > 0; off >>= 1)
            mx = fmaxf(mx, __shfl_xor(mx, off, 64));
        float ex = __expf(myscore - mx);
        float sm = ex;
        #pragma unroll
        for (int off = 16; off > 0; off >>= 1)
            sm += __shfl_xor(sm, off, 64);
        if (l < 32) attn[n * DD + l] = ex / sm;
    }
}

// ---------- fused: buckets, agg = sum_r bucket_r @ RV[r], fc + relu + residual ----------
__global__ void k_agg(const float* __restrict__ center, const float* __restrict__ RVmat,
                      const float* __restrict__ fcw, const float* __restrict__ fcb,
                      const int* __restrict__ adj, const int* __restrict__ rel,
                      const float* __restrict__ attn, float* __restrict__ out) {
    __shared__ float bucket[16 * 8 * 128];   // 64 KB, later reused for agg
    int n0 = blockIdx.x * 16;
    int j = threadIdx.x & 127, h = threadIdx.x >> 7;

    for (int idx = threadIdx.x; idx < 16 * 8 * 128; idx += 256) bucket[idx] = 0.f;
    __syncthreads();

    for (int nn = 0; nn < 8; ++nn) {
        int tn = h * 8 + nn;
        int n = n0 + tn;
        const int* arow = adj + n * DD;
        const int* rrow = rel + n * DD;
        const float* at = attn + n * DD;
        for (int d = 0; d < 32; ++d) {
            int rd = rrow[d];
            int ai = arow[d];
            float a = at[d];
            float xv = 0.f;
            if (ai > 0) xv = center[(size_t)(ai - 1) * UC + j];
            bucket[(tn * 8 + rd) * 128 + j] += a * xv;
        }
    }
    __syncthreads();

    float acc[8];
    #pragma unroll
    for (int nn = 0; nn < 8; ++nn) acc[nn] = 0.f;
    for (int r = 0; r < 8; ++r) {
        for (int kc = 0; kc < 32; ++kc) {
            float4 bv[8];
            #pragma unroll
            for (int nn = 0; nn < 8; ++nn)
                bv[nn] = *(const float4*)&bucket[((h * 8 + nn) * 8 + r) * 128 + kc * 4];
            #pragma unroll
            for (int kk = 0; kk < 4; ++kk) {
                float w = RVmat[(r * UC + kc * 4 + kk) * UC + j];
                #pragma unroll
                for (int nn = 0; nn < 8; ++nn)
                    acc[nn] += ((const float*)&bv[nn])[kk] * w;
            }
        }
    }
    __syncthreads();
    float* agg_s = bucket;   // overlay
    #pragma unroll
    for (int nn = 0; nn < 8; ++nn) agg_s[(h * 8 + nn) * 128 + j] = acc[nn];
    __syncthreads();

    float acc2[8];
    #pragma unroll
    for (int nn = 0; nn < 8; ++nn) acc2[nn] = 0.f;
    for (int kc = 0; kc < 32; ++kc) {
        float4 av[8];
        #pragma unroll
        for (int nn = 0; nn < 8; ++nn)
            av[nn] = *(const float4*)&agg_s[(h * 8 + nn) * 128 + kc * 4];
        #pragma unroll
        for (int kk = 0; kk < 4; ++kk) {
            float w = fcw[(kc * 4 + kk) * UC + j];
            #pragma unroll
            for (int nn = 0; nn < 8; ++nn)
                acc2[nn] += ((const float*)&av[nn])[kk] * w;
        }
    }
    float b = fcb[j];
    #pragma unroll
    for (int nn = 0; nn < 8; ++nn) {
        int n = n0 + h * 8 + nn;
        float v = acc2[nn] + b;
        v = v > 0.f ? v : 0.f;
        out[n * UC + j] = center[n * UC + j] + v;
    }
}

extern "C" void kernel_launch(void* const* d_in, const int* in_sizes, int n_in,
                              void* d_out, int out_size, void* d_ws, size_t ws_size,
                              hipStream_t stream) {
    const float* node_state = (const float*)d_in[0];
    const int*   adjacency  = (const int*)d_in[1];
    const int*   point_enc  = (const int*)d_in[2];
    const int*   relation   = (const int*)d_in[3];
    const float* pew        = (const float*)d_in[4];
    const float* relw       = (const float*)d_in[5];
    const float* qw         = (const float*)d_in[6];
    const float* kw         = (const float*)d_in[7];
    const float* vw         = (const float*)d_in[8];
    const float* fcw        = (const float*)d_in[9];
    const float* fcb        = (const float*)d_in[10];
    float* out = (float*)d_out;

    float* P      = (float*)d_ws;                  // 128*128
    float* Mmat   = P + 128 * 128;                 // 8*128*128
    float* RVmat  = Mmat + 8 * 128 * 128;          // 8*128*128
    float* center = RVmat + 8 * 128 * 128;         // N*128
    float* attn   = center + (size_t)NNODE * UC;   // N*32
    int*   cnt    = (int*)(attn + (size_t)NNODE * DD);
    int*   basep  = cnt + 8;
    int*   cnt2   = basep + 8;
    int*   list   = cnt2 + 8;                      // N ints

    hipMemsetAsync(cnt, 0, 24 * sizeof(int), stream);
    k_qkt<<<64, 256, 0, stream>>>(qw, kw, P);
    k_mrv<<<dim3(8, 8), 256, 0, stream>>>(P, relw, vw, Mmat, RVmat);
    k_count<<<NNODE / 256, 256, 0, stream>>>(point_enc, cnt);
    k_scan<<<1, 64, 0, stream>>>(cnt, basep);
    k_scatter<<<NNODE / 256, 256, 0, stream>>>(point_enc, basep, cnt2, list);
    k_center<<<dim3(NNODE / 32, EC), 256, 0, stream>>>(node_state, pew, list, cnt, basep, center);
    k_scores<<<NNODE / 16, 256, 0, stream>>>(center, Mmat, adjacency, relation, attn);
    k_agg<<<NNODE / 16, 256, 0, stream>>>(center, RVmat, fcw, fcb, adjacency, relation, attn, out);
}